// Round 13
// baseline (115.569 us; speedup 1.0000x reference)
//
#include <hip/hip_runtime.h>

#define BB 2
#define NN 6272
#define CC 256
#define CI 128
#define SEG 7
#define KVSEG (NN / SEG)          // 896 kv per segment
#define KVB 64
#define NIT (KVSEG / KVB)         // 14 iterations of 64 kv
#define LOG2E 1.44269504088896f
#define THR 12.0f                 // defer-max threshold (log2 domain), P <= 4096 fits f16

typedef _Float16 f16;
typedef __attribute__((ext_vector_type(2))) __fp16 fp16v2;   // cvt_pkrtz native type
typedef __attribute__((ext_vector_type(8))) _Float16 f16x8;
typedef __attribute__((ext_vector_type(4))) float f32x4;

// ---------------- kernel 0: weight prep (once, ~3us) ----------------
__global__ __launch_bounds__(256) void prep_kernel(
    const float* __restrict__ Wg, const float* __restrict__ Wt, const float* __restrict__ Wp,
    const float* __restrict__ Wo, const float* __restrict__ bg, const float* __restrict__ bt,
    const float* __restrict__ bp, const float* __restrict__ bo,
    const float* __restrict__ gamma, const float* __restrict__ beta,
    const float* __restrict__ mmean, const float* __restrict__ mvar,
    f16* __restrict__ WallT, f16* __restrict__ WoT,
    float* __restrict__ ball, float* __restrict__ bnsc, float* __restrict__ bnsh)
{
    const int idx = blockIdx.x * 256 + threadIdx.x;
    if (idx < 384*256) {
        const int j = idx >> 8, k = idx & 255;
        float v;
        if (j < 128)      v = Wg[k*CI + j];
        else if (j < 256) v = Wt[k*CI + (j-128)] * LOG2E;
        else              v = Wp[k*CI + (j-256)];
        WallT[j*256 + k] = (f16)v;
    } else if (idx < 384*256 + 256*128) {
        const int i2 = idx - 384*256;
        const int ci = i2 >> 7, k = i2 & 127;
        WoT[ci*CI + k] = (f16)Wo[k*CC + ci];
    } else {
        const int i3 = idx - (384*256 + 256*128);
        if (i3 < 384) {
            float v;
            if (i3 < 128)      v = bg[i3];
            else if (i3 < 256) v = bt[i3-128] * LOG2E;
            else               v = bp[i3-256];
            ball[i3] = v;
        } else if (i3 < 640) {
            const int c = i3 - 384;
            bnsc[c] = gamma[c] * rsqrtf(mvar[c] + 1e-3f);
        } else if (i3 < 896) {
            const int c = i3 - 640;
            float sc = gamma[c] * rsqrtf(mvar[c] + 1e-3f);
            bnsh[c] = beta[c] + sc * (bo[c] - mmean[c]);
        }
    }
}

// ---------------- kernel 1: fused projection GEMM (MFMA), 32-pos tile ----------------
__global__ __launch_bounds__(256) void proj_gemm(
    const float* __restrict__ x, const f16* __restrict__ WallT, const float* __restrict__ ball,
    f16* __restrict__ th, f16* __restrict__ ph, f16* __restrict__ gT)
{
    __shared__ __align__(16) f16 xls[32*264];   // 16.9KB
    __shared__ __align__(16) f16 gls[128*40];   // 10.2KB

    const int tid = threadIdx.x;
    const int wid = tid >> 6, lane = tid & 63;
    const int l15 = lane & 15, lg = lane >> 4;
    const int p0 = blockIdx.x * 32;

    {   // stage x tile 32x256 -> f16 LDS (64B per thread)
        const int row = tid >> 3, c0 = (tid & 7) * 32;
        const float* xsrc = x + (size_t)(p0 + row) * CC + c0;
        f16 buf[32];
        #pragma unroll
        for (int i = 0; i < 8; ++i) {
            float4 v = *reinterpret_cast<const float4*>(xsrc + 4*i);
            buf[4*i+0]=(f16)v.x; buf[4*i+1]=(f16)v.y; buf[4*i+2]=(f16)v.z; buf[4*i+3]=(f16)v.w;
        }
        #pragma unroll
        for (int i = 0; i < 4; ++i)
            *reinterpret_cast<f16x8*>(&xls[row*264 + c0 + 8*i]) =
                *reinterpret_cast<f16x8*>(&buf[8*i]);
    }
    __syncthreads();

    f32x4 acc[2][6];
    #pragma unroll
    for (int pt = 0; pt < 2; ++pt)
        #pragma unroll
        for (int t = 0; t < 6; ++t) acc[pt][t] = (f32x4){0.f,0.f,0.f,0.f};

    const f16* wbase = WallT + (size_t)(wid*96 + l15)*256 + lg*8;
    for (int kk = 0; kk < 8; ++kk) {
        f16x8 a0 = *reinterpret_cast<const f16x8*>(&xls[l15*264 + kk*32 + lg*8]);
        f16x8 a1 = *reinterpret_cast<const f16x8*>(&xls[(16 + l15)*264 + kk*32 + lg*8]);
        #pragma unroll
        for (int t = 0; t < 6; ++t) {
            f16x8 bfr = *reinterpret_cast<const f16x8*>(wbase + (size_t)t*16*256 + kk*32);
            acc[0][t] = __builtin_amdgcn_mfma_f32_16x16x32_f16(a0, bfr, acc[0][t], 0, 0, 0);
            acc[1][t] = __builtin_amdgcn_mfma_f32_16x16x32_f16(a1, bfr, acc[1][t], 0, 0, 0);
        }
    }

    const int bidx = (p0 >= NN) ? 1 : 0;
    const int n0 = p0 - bidx * NN;

    #pragma unroll
    for (int t = 0; t < 6; ++t) {
        const int j0 = wid*96 + t*16;          // + l15 per lane
        const float bv = ball[j0 + l15];
        if (j0 < 128) {          // g -> LDS transpose [ci][pos]
            #pragma unroll
            for (int pt = 0; pt < 2; ++pt)
                #pragma unroll
                for (int r = 0; r < 4; ++r)
                    gls[(j0 + l15)*40 + pt*16 + lg*4 + r] = (f16)(acc[pt][t][r] + bv);
        } else if (j0 < 256) {   // theta (pre-scaled)
            #pragma unroll
            for (int pt = 0; pt < 2; ++pt) {
                f16* dst = th + (size_t)(p0 + pt*16 + lg*4)*CI + (j0 - 128) + l15;
                #pragma unroll
                for (int r = 0; r < 4; ++r)
                    dst[(size_t)r*CI] = (f16)(acc[pt][t][r] + bv);
            }
        } else {                 // phi
            #pragma unroll
            for (int pt = 0; pt < 2; ++pt) {
                f16* dst = ph + (size_t)(p0 + pt*16 + lg*4)*CI + (j0 - 256) + l15;
                #pragma unroll
                for (int r = 0; r < 4; ++r)
                    dst[(size_t)r*CI] = (f16)(acc[pt][t][r] + bv);
            }
        }
    }
    __syncthreads();
    {   // one full contiguous gT tile store (8KB): gT [b][n/32][ci][32]
        const int ci = tid >> 1, half = tid & 1;
        f16x8 v0 = *reinterpret_cast<const f16x8*>(&gls[ci*40 + half*16]);
        f16x8 v1 = *reinterpret_cast<const f16x8*>(&gls[ci*40 + half*16 + 8]);
        f16* gdst = gT + ((size_t)bidx*(NN/32) + (n0 >> 5))*(CI*32) + ci*32 + half*16;
        *reinterpret_cast<f16x8*>(gdst)     = v0;
        *reinterpret_cast<f16x8*>(gdst + 8) = v1;
    }
}

// ---------------- kernel 2: split-KV flash attention, KV tile 64 --------------------
// grid (NN/128, SEG, BB); 4 waves/block; wave owns 32 q rows. 14 iters of 64 kv:
// halved barriers/shfl-reduces vs KVB=32. Corrected XOR swizzles (2-way, free):
//   phi [64][128]: col ^= ((row>>1)&7)<<3   (read key (l15>>1)&7, kvt-independent)
//   g   [128][64]: col ^= 32*(t&1) + 8*(t>>1), t=(row>>2)&3 (spreads across kv-halves)
__global__ __launch_bounds__(256, 2) void attn_kernel(
    const f16* __restrict__ th, const f16* __restrict__ ph,
    const f16* __restrict__ gT, f16* __restrict__ pacc, float* __restrict__ pml)
{
    __shared__ __align__(16) f16 ph_lds[64 * 128];     // 16KB [kv][c], swizzled
    __shared__ __align__(16) f16 g_lds[128 * 64];      // 16KB [ci][kv], swizzled
    __shared__ __align__(16) f16 pT_lds[4][2][16][72]; // 18KB per-wave [qt][q][kv+pad]

    const int b   = blockIdx.z;
    const int seg = blockIdx.y;
    const int tid = threadIdx.x;
    const int wid = tid >> 6;
    const int lane = tid & 63;
    const int l15 = lane & 15;
    const int lg  = lane >> 4;
    const int qw  = blockIdx.x * 128 + wid * 32;

    const f16* thb = th + (size_t)b * NN * CI;
    const f16* phb = ph + (size_t)b * NN * CI;
    const f16* gTb = gT + (size_t)b * (NN/32) * (CI*32);

    // persistent theta B-frags: 2 q-tiles x 4 k-frags
    f16x8 bf[2][4];
    #pragma unroll
    for (int qt = 0; qt < 2; ++qt) {
        const f16* trow = thb + (size_t)(qw + qt*16 + l15) * CI + lg * 8;
        #pragma unroll
        for (int kk = 0; kk < 4; ++kk)
            bf[qt][kk] = *reinterpret_cast<const f16x8*>(trow + kk * 32);
    }

    f32x4 acc[2][8];              // Y^T: per q-tile, 8 ci-tiles, col=q
    f32x4 accl[2];                // row-sums (ones trick)
    float m[2] = {-INFINITY, -INFINITY};
    #pragma unroll
    for (int qt = 0; qt < 2; ++qt) {
        #pragma unroll
        for (int ct = 0; ct < 8; ++ct) acc[qt][ct] = (f32x4){0.f,0.f,0.f,0.f};
        accl[qt] = (f32x4){0.f,0.f,0.f,0.f};
    }

    const f16x8 onesA = {(f16)1,(f16)1,(f16)1,(f16)1,(f16)1,(f16)1,(f16)1,(f16)1};

    // phi staging: 64 rows x 128 c, 4 threads/row (32 f16 each)
    const int prow = tid >> 2, pcol = (tid & 3) * 32;
    const int pX = ((prow >> 1) & 7) << 3;
    // g staging: 128 rows x 64 kv, 2 threads/row; source = two contiguous 8KB tiles
    const int grow = tid >> 1, gcs = (tid & 1) * 16;
    const int gtw = (grow >> 2) & 3;
    const int gX = (gtw & 1) * 32 + (gtw >> 1) * 8;
    // read-side swizzle keys
    const int xswr = ((l15 >> 1) & 7) << 3;             // phi
    const int gtr = (l15 >> 2) & 3;
    const int grX = (gtr & 1) * 32 + (gtr >> 1) * 8;    // g

    const int kv_base = seg * KVSEG;
    const int t0 = kv_base >> 5;            // first 32-kv tile index

    #pragma unroll 1
    for (int it = 0; it < NIT; ++it) {
        const int kv0 = kv_base + it * KVB;

        // ---- issue loads at top (coalesced; g source fully contiguous) ----
        const f16* ps = phb + (size_t)(kv0 + prow) * CI + pcol;
        f16x8 pv0 = *reinterpret_cast<const f16x8*>(ps);
        f16x8 pv1 = *reinterpret_cast<const f16x8*>(ps + 8);
        f16x8 pv2 = *reinterpret_cast<const f16x8*>(ps + 16);
        f16x8 pv3 = *reinterpret_cast<const f16x8*>(ps + 24);
        const f16* gsA = gTb + (size_t)(t0 + 2*it) * (CI*32) + grow*32 + gcs;
        const f16* gsB = gsA + CI*32;
        f16x8 gva0 = *reinterpret_cast<const f16x8*>(gsA);
        f16x8 gva1 = *reinterpret_cast<const f16x8*>(gsA + 8);
        f16x8 gvb0 = *reinterpret_cast<const f16x8*>(gsB);
        f16x8 gvb1 = *reinterpret_cast<const f16x8*>(gsB + 8);

        __syncthreads();
        *reinterpret_cast<f16x8*>(&ph_lds[prow*128 + ((pcol     ) ^ pX)]) = pv0;
        *reinterpret_cast<f16x8*>(&ph_lds[prow*128 + ((pcol +  8) ^ pX)]) = pv1;
        *reinterpret_cast<f16x8*>(&ph_lds[prow*128 + ((pcol + 16) ^ pX)]) = pv2;
        *reinterpret_cast<f16x8*>(&ph_lds[prow*128 + ((pcol + 24) ^ pX)]) = pv3;
        *reinterpret_cast<f16x8*>(&g_lds[grow*64 + ((gcs     ) ^ gX)]) = gva0;
        *reinterpret_cast<f16x8*>(&g_lds[grow*64 + ((gcs +  8) ^ gX)]) = gva1;
        *reinterpret_cast<f16x8*>(&g_lds[grow*64 + ((gcs + 32) ^ gX)]) = gvb0;
        *reinterpret_cast<f16x8*>(&g_lds[grow*64 + ((gcs + 40) ^ gX)]) = gvb1;
        __syncthreads();

        // ---- S^T = phi @ theta^T : 4 kv-tiles x 2 q-tiles ----
        f32x4 s[2][4];
        #pragma unroll
        for (int qt = 0; qt < 2; ++qt)
            #pragma unroll
            for (int kvt = 0; kvt < 4; ++kvt) s[qt][kvt] = (f32x4){0.f,0.f,0.f,0.f};
        #pragma unroll
        for (int kk = 0; kk < 4; ++kk) {
            const int coff = (kk*32 + lg*8) ^ xswr;
            #pragma unroll
            for (int kvt = 0; kvt < 4; ++kvt) {
                f16x8 a = *reinterpret_cast<const f16x8*>(&ph_lds[(kvt*16 + l15)*128 + coff]);
                s[0][kvt] = __builtin_amdgcn_mfma_f32_16x16x32_f16(a, bf[0][kk], s[0][kvt], 0, 0, 0);
                s[1][kvt] = __builtin_amdgcn_mfma_f32_16x16x32_f16(a, bf[1][kk], s[1][kvt], 0, 0, 0);
            }
        }

        // ---- online max per q-tile (lane-local column), defer-rescale ----
        float tm0 = -1e30f, tm1 = -1e30f;
        #pragma unroll
        for (int kvt = 0; kvt < 4; ++kvt)
            #pragma unroll
            for (int r = 0; r < 4; ++r) {
                tm0 = fmaxf(tm0, s[0][kvt][r]);
                tm1 = fmaxf(tm1, s[1][kvt][r]);
            }
        tm0 = fmaxf(tm0, __shfl_xor(tm0, 16));
        tm0 = fmaxf(tm0, __shfl_xor(tm0, 32));
        tm1 = fmaxf(tm1, __shfl_xor(tm1, 16));
        tm1 = fmaxf(tm1, __shfl_xor(tm1, 32));
        if (__any((tm0 > m[0] + THR) || (tm1 > m[1] + THR))) {
            float nm0 = fmaxf(m[0], tm0), nm1 = fmaxf(m[1], tm1);
            float sc0 = __builtin_amdgcn_exp2f(m[0] - nm0);
            float sc1 = __builtin_amdgcn_exp2f(m[1] - nm1);
            m[0] = nm0; m[1] = nm1;
            #pragma unroll
            for (int ct = 0; ct < 8; ++ct) {
                acc[0][ct][0] *= sc0; acc[0][ct][1] *= sc0; acc[0][ct][2] *= sc0; acc[0][ct][3] *= sc0;
                acc[1][ct][0] *= sc1; acc[1][ct][1] *= sc1; acc[1][ct][2] *= sc1; acc[1][ct][3] *= sc1;
            }
            accl[0][0] *= sc0; accl[0][1] *= sc0; accl[0][2] *= sc0; accl[0][3] *= sc0;
            accl[1][0] *= sc1; accl[1][1] *= sc1; accl[1][2] *= sc1; accl[1][3] *= sc1;
        }

        // ---- P^T = exp2(S^T - m), pack f16, exchange via per-wave LDS ----
        #pragma unroll
        for (int qt = 0; qt < 2; ++qt) {
            const float mq = m[qt];
            #pragma unroll
            for (int kvt = 0; kvt < 4; ++kvt) {
                union { fp16v2 h[2]; float2 f; } u;
                u.h[0] = __builtin_amdgcn_cvt_pkrtz(__builtin_amdgcn_exp2f(s[qt][kvt][0] - mq),
                                                    __builtin_amdgcn_exp2f(s[qt][kvt][1] - mq));
                u.h[1] = __builtin_amdgcn_cvt_pkrtz(__builtin_amdgcn_exp2f(s[qt][kvt][2] - mq),
                                                    __builtin_amdgcn_exp2f(s[qt][kvt][3] - mq));
                *reinterpret_cast<float2*>(&pT_lds[wid][qt][l15][kvt*16 + 4*lg]) = u.f;
            }
        }
        asm volatile("s_waitcnt lgkmcnt(0)" ::: "memory");
        f16x8 pa00 = *reinterpret_cast<const f16x8*>(&pT_lds[wid][0][l15][8*lg]);
        f16x8 pa01 = *reinterpret_cast<const f16x8*>(&pT_lds[wid][0][l15][32 + 8*lg]);
        f16x8 pa10 = *reinterpret_cast<const f16x8*>(&pT_lds[wid][1][l15][8*lg]);
        f16x8 pa11 = *reinterpret_cast<const f16x8*>(&pT_lds[wid][1][l15][32 + 8*lg]);

        // ---- Y^T += gT @ P^T (2 kv-halves, swizzled g reads) ----
        #pragma unroll
        for (int ct = 0; ct < 8; ++ct) {
            const f16* gr = &g_lds[(ct*16 + l15)*64];
            f16x8 g0 = *reinterpret_cast<const f16x8*>(&gr[(lg*8) ^ grX]);
            f16x8 g1 = *reinterpret_cast<const f16x8*>(&gr[(32 + lg*8) ^ grX]);
            acc[0][ct] = __builtin_amdgcn_mfma_f32_16x16x32_f16(g0, pa00, acc[0][ct], 0, 0, 0);
            acc[0][ct] = __builtin_amdgcn_mfma_f32_16x16x32_f16(g1, pa01, acc[0][ct], 0, 0, 0);
            acc[1][ct] = __builtin_amdgcn_mfma_f32_16x16x32_f16(g0, pa10, acc[1][ct], 0, 0, 0);
            acc[1][ct] = __builtin_amdgcn_mfma_f32_16x16x32_f16(g1, pa11, acc[1][ct], 0, 0, 0);
        }
        accl[0] = __builtin_amdgcn_mfma_f32_16x16x32_f16(onesA, pa00, accl[0], 0, 0, 0);
        accl[0] = __builtin_amdgcn_mfma_f32_16x16x32_f16(onesA, pa01, accl[0], 0, 0, 0);
        accl[1] = __builtin_amdgcn_mfma_f32_16x16x32_f16(onesA, pa10, accl[1], 0, 0, 0);
        accl[1] = __builtin_amdgcn_mfma_f32_16x16x32_f16(onesA, pa11, accl[1], 0, 0, 0);
    }

    // ---- store NORMALIZED partials (acc/l) as f16: pacc[bs][ci][n] ----
    const float inv[2] = {1.0f / accl[0][0], 1.0f / accl[1][0]};
    #pragma unroll
    for (int qt = 0; qt < 2; ++qt) {
        f16* pb = pacc + (size_t)(b*SEG + seg) * CI * NN + qw + qt*16 + l15;
        #pragma unroll
        for (int ct = 0; ct < 8; ++ct)
            #pragma unroll
            for (int r = 0; r < 4; ++r)
                pb[(size_t)(ct*16 + lg*4 + r) * NN] = (f16)(acc[qt][ct][r] * inv[qt]);
    }

    if (lg == 0) {
        #pragma unroll
        for (int qt = 0; qt < 2; ++qt) {
            float* mlb = pml + ((size_t)(b*SEG + seg) * NN + qw + qt*16 + l15) * 2;
            mlb[0] = m[qt];
            mlb[1] = accl[qt][0];
        }
    }
}

// ---------------- kernel 3: fused combine + out GEMM + BN + residual ----------------
__global__ __launch_bounds__(256) void out_gemm(
    const float* __restrict__ x, const f16* __restrict__ pacc, const float* __restrict__ pml,
    const f16* __restrict__ WoT, const float* __restrict__ bnsc, const float* __restrict__ bnsh,
    float* __restrict__ out)
{
    __shared__ __align__(16) f16 yls[32*136];   // [pos][ci]
    __shared__ float wl_lds[SEG][32];

    const int tid = threadIdx.x;
    const int p0 = blockIdx.x * 32;
    const int bidx = (p0 >= NN) ? 1 : 0;
    const int n0 = p0 - bidx * NN;

    // ---- phase 0: per-position segment weights (32 threads) ----
    if (tid < 32) {
        const int q = n0 + tid;
        float mv[SEG], lv[SEG];
        #pragma unroll
        for (int s = 0; s < SEG; ++s) {
            const float* p = pml + ((size_t)(bidx*SEG + s) * NN + q) * 2;
            mv[s] = p[0];
            lv[s] = p[1];
        }
        float M = mv[0];
        #pragma unroll
        for (int s = 1; s < SEG; ++s) M = fmaxf(M, mv[s]);
        float wl[SEG], wsum = 0.f;
        #pragma unroll
        for (int s = 0; s < SEG; ++s) {
            wl[s] = __builtin_amdgcn_exp2f(mv[s] - M) * lv[s];
            wsum += wl[s];
        }
        const float inv = 1.0f / wsum;
        #pragma unroll
        for (int s = 0; s < SEG; ++s) wl_lds[s][tid] = wl[s] * inv;
    }
    __syncthreads();

    // ---- phase 1: weighted partial-sum; thread owns (ci, 16 pos) ----
    {
        const int ci = tid >> 1, pbase = (tid & 1) * 16;
        float o[16];
        #pragma unroll
        for (int i = 0; i < 16; ++i) o[i] = 0.f;
        for (int s = 0; s < SEG; ++s) {
            const f16* pb = pacc + ((size_t)(bidx*SEG + s) * CI + ci) * NN + n0 + pbase;
            f16x8 v0 = *reinterpret_cast<const f16x8*>(pb);
            f16x8 v1 = *reinterpret_cast<const f16x8*>(pb + 8);
            #pragma unroll
            for (int i = 0; i < 8; ++i) {
                o[i]     = fmaf(wl_lds[s][pbase + i],     (float)v0[i], o[i]);
                o[8 + i] = fmaf(wl_lds[s][pbase + 8 + i], (float)v1[i], o[8 + i]);
            }
        }
        #pragma unroll
        for (int i = 0; i < 16; ++i)
            yls[(pbase + i)*136 + ci] = (f16)o[i];
    }
    __syncthreads();

    // ---- phase 2: GEMM 32 pos x 128 k x 256 ci ----
    const int wid = tid >> 6, lane = tid & 63;
    const int l15 = lane & 15, lg = lane >> 4;

    f32x4 acc[2][4];
    #pragma unroll
    for (int pt = 0; pt < 2; ++pt)
        #pragma unroll
        for (int t = 0; t < 4; ++t) acc[pt][t] = (f32x4){0.f,0.f,0.f,0.f};

    const f16* wb = WoT + (size_t)(wid*64 + l15)*CI + lg*8;
    #pragma unroll
    for (int kk = 0; kk < 4; ++kk) {
        f16x8 a0 = *reinterpret_cast<const f16x8*>(&yls[l15*136 + kk*32 + lg*8]);
        f16x8 a1 = *reinterpret_cast<const f16x8*>(&yls[(16 + l15)*136 + kk*32 + lg*8]);
        #pragma unroll
        for (int t = 0; t < 4; ++t) {
            f16x8 bfr = *reinterpret_cast<const f16x8*>(wb + (size_t)t*16*CI + kk*32);
            acc[0][t] = __builtin_amdgcn_mfma_f32_16x16x32_f16(a0, bfr, acc[0][t], 0, 0, 0);
            acc[1][t] = __builtin_amdgcn_mfma_f32_16x16x32_f16(a1, bfr, acc[1][t], 0, 0, 0);
        }
    }

    #pragma unroll
    for (int t = 0; t < 4; ++t) {
        const int ci = wid*64 + t*16 + l15;
        const float sc = bnsc[ci], sh = bnsh[ci];
        #pragma unroll
        for (int pt = 0; pt < 2; ++pt)
            #pragma unroll
            for (int r = 0; r < 4; ++r) {
                const size_t idx = (size_t)(p0 + pt*16 + lg*4 + r)*CC + ci;
                out[idx] = x[idx] + fmaf(sc, acc[pt][t][r], sh);
            }
    }
}

extern "C" void kernel_launch(void* const* d_in, const int* in_sizes, int n_in,
                              void* d_out, int out_size, void* d_ws, size_t ws_size,
                              hipStream_t stream)
{
    const float* x     = (const float*)d_in[0];
    const float* Wg    = (const float*)d_in[1];
    const float* bg    = (const float*)d_in[2];
    const float* Wt    = (const float*)d_in[3];
    const float* bt    = (const float*)d_in[4];
    const float* Wp    = (const float*)d_in[5];
    const float* bp    = (const float*)d_in[6];
    const float* Wo    = (const float*)d_in[7];
    const float* bo    = (const float*)d_in[8];
    const float* gamma = (const float*)d_in[9];
    const float* beta  = (const float*)d_in[10];
    const float* mmean = (const float*)d_in[11];
    const float* mvar  = (const float*)d_in[12];
    float* out = (float*)d_out;

    const size_t PB = (size_t)BB * NN * CI;                 // 1,605,632
    f16*   th   = (f16*)d_ws;                               // 3.2 MB
    f16*   ph   = th + PB;                                  // 3.2 MB
    f16*   gT   = ph + PB;                                  // 3.2 MB (tiled layout)
    f16*   pacc = gT + PB;                                  // 22.5 MB
    float* pml  = (float*)(pacc + (size_t)BB * SEG * NN * CI);  // 0.7 MB
    f16*   WallT= (f16*)(pml + (size_t)BB * SEG * NN * 2);  // 197 KB
    f16*   WoT  = WallT + 384*256;                          // 66 KB
    float* ball = (float*)(WoT + 256*CI);                   // 1.5 KB
    float* bnsc = ball + 384;
    float* bnsh = bnsc + 256;

    prep_kernel<<<516, 256, 0, stream>>>(Wg, Wt, Wp, Wo, bg, bt, bp, bo,
                                         gamma, beta, mmean, mvar,
                                         WallT, WoT, ball, bnsc, bnsh);
    proj_gemm<<<BB * NN / 32, 256, 0, stream>>>(x, WallT, ball, th, ph, gT);
    attn_kernel<<<dim3(NN / 128, SEG, BB), 256, 0, stream>>>(th, ph, gT, pacc, pml);
    out_gemm<<<BB * NN / 32, 256, 0, stream>>>(x, pacc, pml, WoT, bnsc, bnsh, out);
}